// Round 1
// baseline (8068.250 us; speedup 1.0000x reference)
//
#include <hip/hip_runtime.h>

typedef unsigned short u16;
typedef unsigned int u32;
typedef __attribute__((ext_vector_type(8))) short short8v;   // 8 bf16 (4 VGPR) MFMA frag
typedef __attribute__((ext_vector_type(4))) float f32x4;     // MFMA acc
typedef __attribute__((ext_vector_type(8))) u16 ush8;
typedef __attribute__((ext_vector_type(4))) u16 ush4;

__device__ __forceinline__ u16 f2bf(float x) {               // RNE f32->bf16
  u32 u = __builtin_bit_cast(u32, x);
  return (u16)((u + 0x7FFFu + ((u >> 16) & 1u)) >> 16);
}
__device__ __forceinline__ float bf2f(u16 h) {
  u32 u = ((u32)h) << 16;
  return __builtin_bit_cast(float, u);
}
__device__ __forceinline__ float sigm(float x) { return 1.f / (1.f + expf(-x)); }

// ---------------------------------------------------------------------------
// ConvLSTM recurrence: one WG per (b, row). Computes h for all t, stores
// split-bf16 h_vec rows [t*16+b][4096].  d = r*256 + ch*16 + col.
// ---------------------------------------------------------------------------
__global__ __launch_bounds__(256) void k_conv(int cin, int xmode,
    const float* __restrict__ xin, const float* __restrict__ cw,
    const float* __restrict__ cb, u16* __restrict__ hhi, u16* __restrict__ hlo)
{
  __shared__ float zb[32 * 18];        // cin x (16+2 pad)
  __shared__ float wb[64 * 32 * 3];
  __shared__ float bb[64];
  const int tid = threadIdx.x;
  const int b = blockIdx.x >> 4, r = blockIdx.x & 15;
  const int ch = tid >> 4, col = tid & 15;
  const int cx = cin - 16;
  for (int i = tid; i < 64 * cin * 3; i += 256) wb[i] = cw[i];
  if (tid < 64) bb[tid] = cb[tid];
  for (int i = tid; i < cin * 18; i += 256) zb[i] = 0.f;  // includes pad cols
  __syncthreads();
  float h = 0.f, c = 0.f;
  for (int t = 0; t < 128; ++t) {
    if (xmode == 0) {
      if (ch == 0) zb[col + 1] = xin[((long)b * 128 + t) * 256 + r * 16 + col];
    } else {
      zb[ch * 18 + col + 1] = xin[((long)t * 16 + b) * 4096 + r * 256 + ch * 16 + col];
    }
    zb[(cx + ch) * 18 + col + 1] = h;
    __syncthreads();
    float a0 = bb[ch], a1 = bb[16 + ch], a2 = bb[32 + ch], a3 = bb[48 + ch];
    for (int ic = 0; ic < cin; ++ic) {
      float z0 = zb[ic * 18 + col], z1 = zb[ic * 18 + col + 1], z2 = zb[ic * 18 + col + 2];
      const float* w0 = &wb[((0 * 16 + ch) * cin + ic) * 3];
      const float* w1 = &wb[((1 * 16 + ch) * cin + ic) * 3];
      const float* w2 = &wb[((2 * 16 + ch) * cin + ic) * 3];
      const float* w3 = &wb[((3 * 16 + ch) * cin + ic) * 3];
      a0 += z0 * w0[0] + z1 * w0[1] + z2 * w0[2];
      a1 += z0 * w1[0] + z1 * w1[1] + z2 * w1[2];
      a2 += z0 * w2[0] + z1 * w2[1] + z2 * w2[2];
      a3 += z0 * w3[0] + z1 * w3[1] + z2 * w3[2];
    }
    __syncthreads();
    c = sigm(a1) * c + sigm(a0) * tanhf(a2);   // i,f,g,o gate order
    h = sigm(a3) * tanhf(c);
    long idx = ((long)t * 16 + b) * 4096 + (long)r * 256 + ch * 16 + col;
    u16 hh = f2bf(h);
    hhi[idx] = hh;
    hlo[idx] = f2bf(h - bf2f(hh));
  }
}

// ---------------------------------------------------------------------------
// Transpose + split: W[4096][4096] fp32 (row k, col n) -> WT_hi/lo[n][k] bf16
// ---------------------------------------------------------------------------
__global__ __launch_bounds__(256) void k_tsplit(const float* __restrict__ W,
    u16* __restrict__ hi, u16* __restrict__ lo)
{
  __shared__ float tb[32][33];
  const int tn = blockIdx.x & 127, tk = blockIdx.x >> 7;
  const int n0 = tn * 32, k0 = tk * 32;
  const int lr = threadIdx.x >> 5, lc = threadIdx.x & 31;
  #pragma unroll
  for (int i = 0; i < 4; ++i)
    tb[lr + i * 8][lc] = W[(long)(k0 + lr + i * 8) * 4096 + n0 + lc];
  __syncthreads();
  #pragma unroll
  for (int i = 0; i < 4; ++i) {
    int n = lr + i * 8;
    float v = tb[lc][n];
    long idx = (long)(n0 + n) * 4096 + k0 + lc;
    u16 h = f2bf(v);
    hi[idx] = h;
    lo[idx] = f2bf(v - bf2f(h));
  }
}

// Elementwise split (no transpose) for wv
__global__ __launch_bounds__(256) void k_split(const float* __restrict__ W,
    u16* __restrict__ hi, u16* __restrict__ lo)
{
  long i = ((long)blockIdx.x * 256 + threadIdx.x) * 4;
  const float4 v = *(const float4*)&W[i];
  u16 h0 = f2bf(v.x), h1 = f2bf(v.y), h2 = f2bf(v.z), h3 = f2bf(v.w);
  ush4 hv = {h0, h1, h2, h3};
  ush4 lv = {f2bf(v.x - bf2f(h0)), f2bf(v.y - bf2f(h1)),
             f2bf(v.z - bf2f(h2)), f2bf(v.w - bf2f(h3))};
  *(ush4*)&hi[i] = hv;
  *(ush4*)&lo[i] = lv;
}

// ---------------------------------------------------------------------------
// Split-bf16 GEMM: C[M][4096] = A[M][4096] * B^T, A/B given as hi/lo bf16,
// 3-MFMA compensation (hh + hl + lh). 128x128 tile, 4 waves (2x2 quadrants).
// mode 0: write f32 C.  mode 1: write split hi/lo bf16 C.
// grid.x = (M/128)*32
// ---------------------------------------------------------------------------
__global__ __launch_bounds__(256) void k_gemm(
    const u16* __restrict__ Ahi, const u16* __restrict__ Alo,
    const u16* __restrict__ Bhi, const u16* __restrict__ Blo,
    float* __restrict__ Cf, u16* __restrict__ Chi, u16* __restrict__ Clo,
    int mode)
{
  constexpr int LSTR = 56;  // padded row stride (u16): 112B, 16B-aligned, ~2-way banks
  __shared__ __align__(16) u16 lds[4 * 128 * LSTR];
  const int nT = blockIdx.x & 31;
  const int mT = blockIdx.x >> 5;
  const int tid = threadIdx.x;
  const int lane = tid & 63;
  const int wave = tid >> 6;
  const int waveM = wave >> 1, waveN = wave & 1;
  const long aRow0 = (long)mT * 128;
  const long bRow0 = (long)nT * 128;

  f32x4 acc[4][4] = {};

  // staging map: 512 slots of 8 u16 per array; thread covers slots tid, tid+256
  const int w0 = tid, w1 = tid + 256;
  const int r0 = w0 >> 2, kc0 = (w0 & 3) * 8;
  const int r1 = w1 >> 2, kc1 = (w1 & 3) * 8;

  ush8 rg[8];
  // preload k0 = 0
  {
    rg[0] = *(const ush8*)(Ahi + (aRow0 + r0) * 4096 + kc0);
    rg[1] = *(const ush8*)(Alo + (aRow0 + r0) * 4096 + kc0);
    rg[2] = *(const ush8*)(Bhi + (bRow0 + r0) * 4096 + kc0);
    rg[3] = *(const ush8*)(Blo + (bRow0 + r0) * 4096 + kc0);
    rg[4] = *(const ush8*)(Ahi + (aRow0 + r1) * 4096 + kc1);
    rg[5] = *(const ush8*)(Alo + (aRow0 + r1) * 4096 + kc1);
    rg[6] = *(const ush8*)(Bhi + (bRow0 + r1) * 4096 + kc1);
    rg[7] = *(const ush8*)(Blo + (bRow0 + r1) * 4096 + kc1);
  }
  const int kk = (lane >> 4) * 8;

  for (int k0 = 0; k0 < 4096; k0 += 32) {
    __syncthreads();  // previous iter's frag reads done
    *(ush8*)&lds[0 * 128 * LSTR + r0 * LSTR + kc0] = rg[0];
    *(ush8*)&lds[1 * 128 * LSTR + r0 * LSTR + kc0] = rg[1];
    *(ush8*)&lds[2 * 128 * LSTR + r0 * LSTR + kc0] = rg[2];
    *(ush8*)&lds[3 * 128 * LSTR + r0 * LSTR + kc0] = rg[3];
    *(ush8*)&lds[0 * 128 * LSTR + r1 * LSTR + kc1] = rg[4];
    *(ush8*)&lds[1 * 128 * LSTR + r1 * LSTR + kc1] = rg[5];
    *(ush8*)&lds[2 * 128 * LSTR + r1 * LSTR + kc1] = rg[6];
    *(ush8*)&lds[3 * 128 * LSTR + r1 * LSTR + kc1] = rg[7];
    __syncthreads();
    if (k0 + 32 < 4096) {  // prefetch next k-tile (overlaps MFMA below)
      int kn = k0 + 32;
      rg[0] = *(const ush8*)(Ahi + (aRow0 + r0) * 4096 + kn + kc0);
      rg[1] = *(const ush8*)(Alo + (aRow0 + r0) * 4096 + kn + kc0);
      rg[2] = *(const ush8*)(Bhi + (bRow0 + r0) * 4096 + kn + kc0);
      rg[3] = *(const ush8*)(Blo + (bRow0 + r0) * 4096 + kn + kc0);
      rg[4] = *(const ush8*)(Ahi + (aRow0 + r1) * 4096 + kn + kc1);
      rg[5] = *(const ush8*)(Alo + (aRow0 + r1) * 4096 + kn + kc1);
      rg[6] = *(const ush8*)(Bhi + (bRow0 + r1) * 4096 + kn + kc1);
      rg[7] = *(const ush8*)(Blo + (bRow0 + r1) * 4096 + kn + kc1);
    }
    short8v bh[4], bl[4];
    #pragma unroll
    for (int j = 0; j < 4; ++j) {
      int brow = waveN * 64 + j * 16 + (lane & 15);
      bh[j] = *(const short8v*)&lds[2 * 128 * LSTR + brow * LSTR + kk];
      bl[j] = *(const short8v*)&lds[3 * 128 * LSTR + brow * LSTR + kk];
    }
    #pragma unroll
    for (int i = 0; i < 4; ++i) {
      int arow = waveM * 64 + i * 16 + (lane & 15);
      short8v ah = *(const short8v*)&lds[0 * 128 * LSTR + arow * LSTR + kk];
      short8v al = *(const short8v*)&lds[1 * 128 * LSTR + arow * LSTR + kk];
      #pragma unroll
      for (int j = 0; j < 4; ++j) {
        acc[i][j] = __builtin_amdgcn_mfma_f32_16x16x32_bf16(ah, bh[j], acc[i][j], 0, 0, 0);
        acc[i][j] = __builtin_amdgcn_mfma_f32_16x16x32_bf16(ah, bl[j], acc[i][j], 0, 0, 0);
        acc[i][j] = __builtin_amdgcn_mfma_f32_16x16x32_bf16(al, bh[j], acc[i][j], 0, 0, 0);
      }
    }
  }
  // epilogue: D row=(lane>>4)*4+reg, col=lane&15 (measured m89 layout)
  const long row0 = aRow0 + waveM * 64;
  const long col0 = bRow0 + waveN * 64;
  #pragma unroll
  for (int i = 0; i < 4; ++i)
    #pragma unroll
    for (int j = 0; j < 4; ++j) {
      long rr = row0 + i * 16 + ((lane >> 4) * 4);
      long cc = col0 + j * 16 + (lane & 15);
      #pragma unroll
      for (int g = 0; g < 4; ++g) {
        float v = acc[i][j][g];
        long idx = (rr + g) * 4096 + cc;
        if (mode == 0) {
          Cf[idx] = v;
        } else {
          u16 h = f2bf(v);
          Chi[idx] = h;
          Clo[idx] = f2bf(v - bf2f(h));
        }
      }
    }
}

// ---------------------------------------------------------------------------
// Scores: S[b][t][t'] = sum_d Q[t][b][d] * K[t'][b][d]  (fp32, exact-ish)
// grid: b(16) x ti(4) x tj(4) = 256 WGs; 32x32 output tile, K chunked by 128.
// ---------------------------------------------------------------------------
__global__ __launch_bounds__(256) void k_scores(const float* __restrict__ Q,
    const float* __restrict__ Km, float* __restrict__ S)
{
  __shared__ float Qc[32][132];
  __shared__ float Kc[32][132];
  const int bx = blockIdx.x;
  const int b = bx >> 4, ti = (bx >> 2) & 3, tj = bx & 3;
  const int tid = threadIdx.x;
  const int dt = tid >> 3, jg = tid & 7;
  float acc0 = 0.f, acc1 = 0.f, acc2 = 0.f, acc3 = 0.f;
  for (int k0 = 0; k0 < 4096; k0 += 128) {
    #pragma unroll
    for (int p = 0; p < 4; ++p) {
      int s = tid + p * 256;               // 1024 float4 slots
      int rr = s >> 5, kq = (s & 31) * 4;
      *(float4*)&Qc[rr][kq] = *(const float4*)&Q[((long)(ti * 32 + rr) * 16 + b) * 4096 + k0 + kq];
      *(float4*)&Kc[rr][kq] = *(const float4*)&Km[((long)(tj * 32 + rr) * 16 + b) * 4096 + k0 + kq];
    }
    __syncthreads();
    #pragma unroll 4
    for (int kq = 0; kq < 128; ++kq) {
      float qv = Qc[dt][kq];
      acc0 += qv * Kc[jg * 4 + 0][kq];
      acc1 += qv * Kc[jg * 4 + 1][kq];
      acc2 += qv * Kc[jg * 4 + 2][kq];
      acc3 += qv * Kc[jg * 4 + 3][kq];
    }
    __syncthreads();
  }
  long base = ((long)b * 128 + ti * 32 + dt) * 128 + tj * 32 + jg * 4;
  S[base + 0] = acc0; S[base + 1] = acc1; S[base + 2] = acc2; S[base + 3] = acc3;
}

// Softmax over strictly-past scores -> Wx[t][b][t']  (zero row at t=0)
__global__ __launch_bounds__(256) void k_softmax(const float* __restrict__ S,
    float* __restrict__ Wx)
{
  const int wv = threadIdx.x >> 6, lane = threadIdx.x & 63;
  const int idx = blockIdx.x * 4 + wv;        // = b*128 + t
  const int b = idx >> 7, t = idx & 127;
  const float* row = &S[(long)idx * 128];
  float v0 = (lane < t) ? row[lane] * 0.015625f : -1e30f;
  float v1 = (lane + 64 < t) ? row[lane + 64] * 0.015625f : -1e30f;
  float m = fmaxf(v0, v1);
  #pragma unroll
  for (int off = 32; off; off >>= 1) m = fmaxf(m, __shfl_xor(m, off));
  float e0 = (lane < t) ? expf(v0 - m) : 0.f;
  float e1 = (lane + 64 < t) ? expf(v1 - m) : 0.f;
  float s = e0 + e1;
  #pragma unroll
  for (int off = 32; off; off >>= 1) s += __shfl_xor(s, off);
  float inv = 1.f / fmaxf(s, 1e-9f);
  float* wr = &Wx[((long)t * 16 + b) * 128];
  wr[lane] = e0 * inv;
  wr[lane + 64] = e1 * inv;
}

// out_0 = tanh(ho_0); writes f32 dest + split-bf16 step buffer
__global__ __launch_bounds__(256) void k_prologue(const float* __restrict__ HO,
    float* __restrict__ fdest, int dmode, u16* __restrict__ ohi, u16* __restrict__ olo)
{
  int i = blockIdx.x * 256 + threadIdx.x;   // b*4096 + d, 65536 total
  float v = tanhf(HO[i]);
  u16 h = f2bf(v);
  ohi[i] = h;
  olo[i] = f2bf(v - bf2f(h));
  if (dmode == 0) fdest[i] = v;
  else {
    int b = i >> 12, d = i & 4095;
    fdest[(long)b * 128 * 4096 + d] = v;    // d_out[b][0][d]
  }
}

// ---------------------------------------------------------------------------
// Sequential step t: vo_t = out_t @ Wvo (split MFMA), then
// out_{t+1} = tanh(ho_{t+1} + sum_{t'<=t} w[t+1][b][t'] * vo_{t'}).
// grid 256 WGs, 16 output cols each, 4 waves split K into quarters.
// ---------------------------------------------------------------------------
__global__ __launch_bounds__(256) void k_step(int t,
    const u16* __restrict__ Wvh, const u16* __restrict__ Wvl,
    const float* __restrict__ Wx, const float* __restrict__ HO,
    float* __restrict__ VO,
    const u16* __restrict__ ihi, const u16* __restrict__ ilo,
    u16* __restrict__ ohi, u16* __restrict__ olo,
    float* __restrict__ fdest, int dmode)
{
  constexpr int LSTR = 136;  // 272B stride: 16B-aligned, 2-way banks
  __shared__ __align__(16) u16 lds[4 * 16 * LSTR];
  __shared__ float vo_w[4][256];
  const int tid = threadIdx.x;
  const int lane = tid & 63;
  const int wave = tid >> 6;
  const int n0 = blockIdx.x * 16;
  f32x4 acc = {0.f, 0.f, 0.f, 0.f};

  const int srow = tid >> 4;          // 0..15
  const int skc = (tid & 15) * 8;     // 0..120
  const u16* gA0 = ihi + (long)srow * 4096 + skc;
  const u16* gA1 = ilo + (long)srow * 4096 + skc;
  const u16* gB0 = Wvh + (long)(n0 + srow) * 4096 + skc;
  const u16* gB1 = Wvl + (long)(n0 + srow) * 4096 + skc;
  const int ldsi = srow * LSTR + skc;
  const int fa = (lane & 15) * LSTR + wave * 32 + (lane >> 4) * 8;

  ush8 ra0[4], ra1[4];
  ra0[0] = *(const ush8*)(gA0); ra0[1] = *(const ush8*)(gA1);
  ra0[2] = *(const ush8*)(gB0); ra0[3] = *(const ush8*)(gB1);
  ra1[0] = *(const ush8*)(gA0 + 128); ra1[1] = *(const ush8*)(gA1 + 128);
  ra1[2] = *(const ush8*)(gB0 + 128); ra1[3] = *(const ush8*)(gB1 + 128);

  for (int c = 0; c < 32; c += 2) {
    __syncthreads();
    *(ush8*)&lds[0 * 16 * LSTR + ldsi] = ra0[0];
    *(ush8*)&lds[1 * 16 * LSTR + ldsi] = ra0[1];
    *(ush8*)&lds[2 * 16 * LSTR + ldsi] = ra0[2];
    *(ush8*)&lds[3 * 16 * LSTR + ldsi] = ra0[3];
    __syncthreads();
    if (c + 2 < 32) {
      int off = (c + 2) * 128;
      ra0[0] = *(const ush8*)(gA0 + off); ra0[1] = *(const ush8*)(gA1 + off);
      ra0[2] = *(const ush8*)(gB0 + off); ra0[3] = *(const ush8*)(gB1 + off);
    }
    {
      short8v ah = *(const short8v*)&lds[0 * 16 * LSTR + fa];
      short8v al = *(const short8v*)&lds[1 * 16 * LSTR + fa];
      short8v bh = *(const short8v*)&lds[2 * 16 * LSTR + fa];
      short8v bl = *(const short8v*)&lds[3 * 16 * LSTR + fa];
      acc = __builtin_amdgcn_mfma_f32_16x16x32_bf16(ah, bh, acc, 0, 0, 0);
      acc = __builtin_amdgcn_mfma_f32_16x16x32_bf16(ah, bl, acc, 0, 0, 0);
      acc = __builtin_amdgcn_mfma_f32_16x16x32_bf16(al, bh, acc, 0, 0, 0);
    }
    __syncthreads();
    *(ush8*)&lds[0 * 16 * LSTR + ldsi] = ra1[0];
    *(ush8*)&lds[1 * 16 * LSTR + ldsi] = ra1[1];
    *(ush8*)&lds[2 * 16 * LSTR + ldsi] = ra1[2];
    *(ush8*)&lds[3 * 16 * LSTR + ldsi] = ra1[3];
    __syncthreads();
    if (c + 3 < 32) {
      int off = (c + 3) * 128;
      ra1[0] = *(const ush8*)(gA0 + off); ra1[1] = *(const ush8*)(gA1 + off);
      ra1[2] = *(const ush8*)(gB0 + off); ra1[3] = *(const ush8*)(gB1 + off);
    }
    {
      short8v ah = *(const short8v*)&lds[0 * 16 * LSTR + fa];
      short8v al = *(const short8v*)&lds[1 * 16 * LSTR + fa];
      short8v bh = *(const short8v*)&lds[2 * 16 * LSTR + fa];
      short8v bl = *(const short8v*)&lds[3 * 16 * LSTR + fa];
      acc = __builtin_amdgcn_mfma_f32_16x16x32_bf16(ah, bh, acc, 0, 0, 0);
      acc = __builtin_amdgcn_mfma_f32_16x16x32_bf16(ah, bl, acc, 0, 0, 0);
      acc = __builtin_amdgcn_mfma_f32_16x16x32_bf16(al, bh, acc, 0, 0, 0);
    }
  }
  // reduce 4 wave-partials (k quarters) -> vo_t[b][col]
  #pragma unroll
  for (int g = 0; g < 4; ++g)
    vo_w[wave][((lane >> 4) * 4 + g) * 16 + (lane & 15)] = acc[g];
  __syncthreads();
  const int b = tid >> 4, col = tid & 15;
  float v = vo_w[0][tid] + vo_w[1][tid] + vo_w[2][tid] + vo_w[3][tid];
  VO[((long)t * 16 + b) * 4096 + n0 + col] = v;

  // mix + tanh for step t+1 (this WG's cols only; vo_t taken from register)
  if (t < 127) {
    const float* wrow = &Wx[((long)(t + 1) * 16 + b) * 128];
    const float* vcol = &VO[(long)b * 4096 + n0 + col];
    float ctx = 0.f, ctx2 = 0.f;
    int tp = 0;
    #pragma unroll 4
    for (; tp + 1 < t; tp += 2) {
      ctx  += wrow[tp]     * vcol[(long)tp * 65536];
      ctx2 += wrow[tp + 1] * vcol[(long)(tp + 1) * 65536];
    }
    if (tp < t) ctx += wrow[tp] * vcol[(long)tp * 65536];
    ctx += ctx2 + wrow[t] * v;
    float ho = HO[((long)(t + 1) * 16 + b) * 4096 + n0 + col];
    float o = tanhf(ho + ctx);
    long oi = (long)b * 4096 + n0 + col;
    u16 hh = f2bf(o);
    ohi[oi] = hh;
    olo[oi] = f2bf(o - bf2f(hh));
    if (dmode == 0) fdest[((long)(t + 1) * 16 + b) * 4096 + n0 + col] = o;
    else            fdest[((long)b * 128 + (t + 1)) * 4096 + n0 + col] = o;
  }
}

// ---------------------------------------------------------------------------
extern "C" void kernel_launch(void* const* d_in, const int* in_sizes, int n_in,
                              void* d_out, int out_size, void* d_ws, size_t ws_size,
                              hipStream_t stream)
{
  (void)in_sizes; (void)n_in; (void)out_size;
  if (ws_size < 472383488UL) return;  // need ~451 MiB scratch
  char* ws = (char*)d_ws;
  u16* WT_hi = (u16*)(ws + 0UL);
  u16* WT_lo = (u16*)(ws + 33554432UL);
  u16* WV_hi = (u16*)(ws + 67108864UL);
  u16* WV_lo = (u16*)(ws + 100663296UL);
  u16* Wvo_hi[2] = {(u16*)(ws + 134217728UL), (u16*)(ws + 201326592UL)};
  u16* Wvo_lo[2] = {(u16*)(ws + 167772160UL), (u16*)(ws + 234881024UL)};
  u16* Hs_hi = (u16*)(ws + 268435456UL);
  u16* Hs_lo = (u16*)(ws + 285212672UL);
  float* Qf   = (float*)(ws + 301989888UL);
  float* Kf   = (float*)(ws + 335544320UL);
  float* HOb  = (float*)(ws + 369098752UL);
  float* Sb   = (float*)(ws + 402653184UL);
  float* Wmx  = (float*)(ws + 403701760UL);
  float* VOb  = (float*)(ws + 404750336UL);
  float* OUT0 = (float*)(ws + 438304768UL);
  u16* obh[2] = {(u16*)(ws + 471859200UL), (u16*)(ws + 472121344UL)};
  u16* obl[2] = {(u16*)(ws + 471990272UL), (u16*)(ws + 472252416UL)};
  float* dout = (float*)d_out;
  const float* x_flat = (const float*)d_in[0];

  for (int l = 0; l < 2; ++l) {
    const float* cw = (const float*)d_in[1 + l * 6];
    const float* cb = (const float*)d_in[2 + l * 6];
    const float* wq = (const float*)d_in[3 + l * 6];
    const float* wk = (const float*)d_in[4 + l * 6];
    const float* wv = (const float*)d_in[5 + l * 6];
    const float* wo = (const float*)d_in[6 + l * 6];
    const int cin = (l == 0) ? 17 : 32;

    // Phase A: ConvLSTM recurrence -> split h_vec rows
    hipLaunchKernelGGL(k_conv, dim3(256), dim3(256), 0, stream,
        cin, l, (l == 0) ? x_flat : OUT0, cw, cb, Hs_hi, Hs_lo);

    // Phase B: batched GEMMs (Q, K, HO) + composite Wvo = wv @ wo_c
    hipLaunchKernelGGL(k_tsplit, dim3(16384), dim3(256), 0, stream, wq, WT_hi, WT_lo);
    hipLaunchKernelGGL(k_gemm, dim3(512), dim3(256), 0, stream,
        Hs_hi, Hs_lo, WT_hi, WT_lo, Qf, (u16*)nullptr, (u16*)nullptr, 0);
    hipLaunchKernelGGL(k_tsplit, dim3(16384), dim3(256), 0, stream, wk, WT_hi, WT_lo);
    hipLaunchKernelGGL(k_gemm, dim3(512), dim3(256), 0, stream,
        Hs_hi, Hs_lo, WT_hi, WT_lo, Kf, (u16*)nullptr, (u16*)nullptr, 0);
    hipLaunchKernelGGL(k_tsplit, dim3(16384), dim3(256), 0, stream, wo, WT_hi, WT_lo);
    hipLaunchKernelGGL(k_gemm, dim3(512), dim3(256), 0, stream,
        Hs_hi, Hs_lo, WT_hi, WT_lo, HOb, (u16*)nullptr, (u16*)nullptr, 0);
    hipLaunchKernelGGL(k_tsplit, dim3(16384), dim3(256), 0, stream,
        wo + 16777216UL, WT_hi, WT_lo);                       // wo_c^T
    hipLaunchKernelGGL(k_split, dim3(16384), dim3(256), 0, stream, wv, WV_hi, WV_lo);
    // WvoT[n][k] = sum_m wo_c[m][n] * wv[k][m]
    hipLaunchKernelGGL(k_gemm, dim3(1024), dim3(256), 0, stream,
        WT_hi, WT_lo, WV_hi, WV_lo, (float*)nullptr, Wvo_hi[l], Wvo_lo[l], 1);

    // Scores + softmax (all precomputable from h)
    hipLaunchKernelGGL(k_scores, dim3(256), dim3(256), 0, stream, Qf, Kf, Sb);
    hipLaunchKernelGGL(k_softmax, dim3(512), dim3(256), 0, stream, Sb, Wmx);

    // Phase C: sequential attention/value recurrence
    hipLaunchKernelGGL(k_prologue, dim3(256), dim3(256), 0, stream,
        HOb, (l == 0) ? OUT0 : dout, l, obh[0], obl[0]);
    for (int t = 0; t < 127; ++t) {
      hipLaunchKernelGGL(k_step, dim3(256), dim3(256), 0, stream,
          t, Wvo_hi[l], Wvo_lo[l], Wmx, HOb, VOb,
          obh[t & 1], obl[t & 1], obh[(t + 1) & 1], obl[(t + 1) & 1],
          (l == 0) ? OUT0 : dout, l);
    }
  }
}